// Round 2
// baseline (342.475 us; speedup 1.0000x reference)
//
#include <hip/hip_runtime.h>
#include <cstdint>
#include <cstddef>

// MI355X self-attention: B=4 S=2048 E=1024 H=16 D=64
// R9: GEMM template redesigned after R8 post-mortem:
//  - BM=128 BN=256 BK=64, 512 thr / 8 waves (2Mx4N), per-wave 64x64.
//  - grid qkv 768 (=3 exact rounds), gemm_out 256 (=1 round): no tail waste.
//  - A dbuf (32KB) + B tri-buf (96KB) = 128KB LDS; B prefetched 2 K-tiles
//    ahead into its own buffer (no same-buffer overwrite trick).
//  - 2 phases/K-tile: {8 ds_read_b128; stage; s_barrier; setprio1; 16 MFMA;
//    setprio0; s_barrier}; counted vmcnt(4) once per K-tile (never 0).
//  - NO lgkmcnt(0)/sched_barrier fences: compiler-visible ds_reads get
//    counted lgkm waits and interleave with MFMA (R8's fences serialized
//    the whole CU per phase -> 17% MfmaUtil).
// attn/prepass/transpose_v unchanged from R8 (passing).

typedef __attribute__((ext_vector_type(8))) short short8;   // 8 x bf16
typedef __attribute__((ext_vector_type(4))) float float4_;
typedef unsigned int u32;
typedef unsigned short u16;

__device__ __forceinline__ u16 f2b(float f) {
  u32 u = __float_as_uint(f);
  u += 0x7FFFu + ((u >> 16) & 1u);   // RNE
  return (u16)(u >> 16);
}

__device__ __forceinline__ float fexp2(float x) {
#if __has_builtin(__builtin_amdgcn_exp2f)
  return __builtin_amdgcn_exp2f(x);   // bare v_exp_f32
#else
  return exp2f(x);
#endif
}

// pack (lo,hi) floats -> bf16x2 by truncation (1 v_perm)
__device__ __forceinline__ u32 pk_trunc(float lo, float hi) {
#if __has_builtin(__builtin_amdgcn_perm)
  return __builtin_amdgcn_perm(__float_as_uint(hi), __float_as_uint(lo), 0x07060302);
#else
  return (__float_as_uint(hi) & 0xFFFF0000u) | (__float_as_uint(lo) >> 16);
#endif
}

#if __has_builtin(__builtin_amdgcn_fdot2_f32_bf16)
typedef __bf16 bf16x2 __attribute__((ext_vector_type(2)));
__device__ __forceinline__ float accum_pk(u32 pk, float acc) {
  bf16x2 p = __builtin_bit_cast(bf16x2, pk);
  bf16x2 one = __builtin_bit_cast(bf16x2, (u32)0x3F803F80u);
  return __builtin_amdgcn_fdot2_f32_bf16(p, one, acc, false);
}
#else
__device__ __forceinline__ float accum_pk(u32 pk, float acc) {
  return acc + __uint_as_float(pk << 16) + __uint_as_float(pk & 0xFFFF0000u);
}
#endif

// async global->LDS, 16B per lane; LDS dst must be wave-uniform base + lane*16
__device__ __forceinline__ void async_cp16(const void* g, void* l) {
  __builtin_amdgcn_global_load_lds(
      (const __attribute__((address_space(1))) u32*)g,
      (__attribute__((address_space(3))) u32*)l, 16, 0, 0);
}

// ---------------- fused pre-pass ----------------
// blocks [0,8192): cvt x->bf16; [8192,11264): transpose w_qkv; rest: w_out.

__device__ __forceinline__ void transpose_block(const float* __restrict__ in,
                                                u16* __restrict__ out,
                                                int R, int C, int bx, int by,
                                                float t[32][33]) {
  int tx = threadIdx.x & 31, ty = threadIdx.x >> 5;
  int r0 = by * 32, c0 = bx * 32;
#pragma unroll
  for (int k = 0; k < 4; k++)
    t[ty + 8 * k][tx] = in[(size_t)(r0 + ty + 8 * k) * C + c0 + tx];
  __syncthreads();
#pragma unroll
  for (int k = 0; k < 4; k++)
    out[(size_t)(c0 + ty + 8 * k) * R + r0 + tx] = f2b(t[tx][ty + 8 * k]);
}

__global__ void prepass_kernel(const float* __restrict__ x, u16* __restrict__ Xb,
                               const float* __restrict__ wqkv, u16* __restrict__ Wqt,
                               const float* __restrict__ wout, u16* __restrict__ Wot) {
  __shared__ float t[32][33];
  int gid = blockIdx.x;
  if (gid < 8192) {
    int i = gid * 256 + threadIdx.x;
    float4 v = ((const float4*)x)[i];
    uint2 p;
    p.x = (u32)f2b(v.x) | ((u32)f2b(v.y) << 16);
    p.y = (u32)f2b(v.z) | ((u32)f2b(v.w) << 16);
    ((uint2*)Xb)[i] = p;
  } else if (gid < 11264) {
    int j = gid - 8192;
    transpose_block(wqkv, Wqt, 1024, 3072, j % 96, j / 96, t);
  } else {
    int j = gid - 11264;
    transpose_block(wout, Wot, 1024, 1024, j % 32, j / 32, t);
  }
}

// V[bh][s][d] bf16 -> Vt[bh][d][s] bf16. 64x64 tiles. grid (32, 64), block 256.
__global__ void transpose_v(const u16* __restrict__ V, u16* __restrict__ Vt) {
  __shared__ u16 t[64][80];
  int bh = blockIdx.y, s0 = blockIdx.x * 64;
  const u16* Vh = V + (size_t)bh * 2048 * 64;
  u16* Vth = Vt + (size_t)bh * 64 * 2048;
  int tr = threadIdx.x >> 3;            // 0..31
  int tc = (threadIdx.x & 7) * 8;       // 0..56 step 8
#pragma unroll
  for (int p = 0; p < 2; p++) {
    int r = p * 32 + tr;
    *(uint4*)&t[r][tc] = *(const uint4*)(Vh + (size_t)(s0 + r) * 64 + tc);
  }
  __syncthreads();
#pragma unroll
  for (int p = 0; p < 2; p++) {
    int d = p * 32 + tr;
    u16 tmp[8];
#pragma unroll
    for (int k = 0; k < 8; k++) tmp[k] = t[tc + k][d];
    *(uint4*)(Vth + (size_t)d * 2048 + s0 + tc) = *(uint4*)tmp;
  }
}

// ---------------- gemm_qkv: 128x256 tile, BK=64, 2-phase counted-vmcnt ----------------
// LDS fragment-major chunks: chunk fl = fr*2+ks holds M[base+fr*16+lr][ks*32+lq*8..+8]
// at lX[buf][fl*64 + lane] (1KB contiguous per chunk -> conflict-free b128 reads,
// linear global_load_lds dest with per-lane pre-swizzled global source).
// Per K-tile u: P1(ks0): reads A x4 + B x4, stage A(u+1)->lA[buf^1] (2 loads);
//               P2(ks1): reads A x4 + B x4, stage B(u+2)->lB[(u+2)%3] (4 loads);
//               vmcnt(4) after P2 MFMA (keeps B(u+2) in flight), barrier.

__global__ __launch_bounds__(512, 2) void gemm_qkv_kernel(
    const u16* __restrict__ A, const u16* __restrict__ Bt,
    u16* __restrict__ QKV) {   // QKV = 3 x 16MB consecutive [b,h,s,d] buffers
  const int K = 1024;
  const int NT = 16;                  // K / 64
  __shared__ short8 lA[2][1024];      // 32 KB
  __shared__ short8 lB[3][2048];      // 96 KB
  int tid = threadIdx.x;
  int wid = tid >> 6, l = tid & 63, lr = l & 15, lq = l >> 4;
  int wm = wid >> 2, wn = wid & 3;    // 2 x 4 wave grid
  int gid = blockIdx.x;
  int xcd = gid & 7, j = gid >> 3;    // 96 blocks per XCD
  int nt = j % 12, mt = xcd * 8 + j / 12;
  int m0 = mt * 128, n0 = nt * 256;

  float4_ acc[4][4] = {};

  const u16* srcA[2];
  const u16* srcB[4];
#pragma unroll
  for (int s = 0; s < 2; s++) {
    int fl = s * 8 + wid;
    srcA[s] = A + (size_t)(m0 + (fl >> 1) * 16 + lr) * K + (fl & 1) * 32 + lq * 8;
  }
#pragma unroll
  for (int s = 0; s < 4; s++) {
    int fl = s * 8 + wid;
    srcB[s] = Bt + (size_t)(n0 + (fl >> 1) * 16 + lr) * K + (fl & 1) * 32 + lq * 8;
  }

  auto stageA = [&](int buf, int k0) {
#pragma unroll
    for (int s = 0; s < 2; s++)
      async_cp16(srcA[s] + k0, &lA[buf][(s * 8 + wid) * 64 + l]);
  };
  auto stageB = [&](int bb, int k0) {
#pragma unroll
    for (int s = 0; s < 4; s++)
      async_cp16(srcB[s] + k0, &lB[bb][(s * 8 + wid) * 64 + l]);
  };

  // prologue: A(0), B(0), B(1) issued (10 loads); vmcnt(4) => A(0),B(0) landed
  stageA(0, 0);
  stageB(0, 0);
  stageB(1, 64);
  asm volatile("s_waitcnt vmcnt(4)" ::: "memory");
  __builtin_amdgcn_s_barrier();

  for (int u = 0; u < NT; ++u) {
    int buf = u & 1;
    int vb = u % 3;
    int kA = (u + 1 < NT ? u + 1 : NT - 1) * 64;   // clamp => L2-warm dummy at tail
    int kB = (u + 2 < NT ? u + 2 : NT - 1) * 64;
    short8 af[4], bf[4];

    // ---- P1 (ks=0): stage A(u+1) ----
#pragma unroll
    for (int mf = 0; mf < 4; mf++) af[mf] = lA[buf][((wm * 4 + mf) * 2 + 0) * 64 + l];
#pragma unroll
    for (int nf = 0; nf < 4; nf++) bf[nf] = lB[vb][((wn * 4 + nf) * 2 + 0) * 64 + l];
    stageA(buf ^ 1, kA);
    __builtin_amdgcn_s_barrier();
    __builtin_amdgcn_s_setprio(1);
#pragma unroll
    for (int mf = 0; mf < 4; mf++)
#pragma unroll
      for (int nf = 0; nf < 4; nf++)
        acc[mf][nf] = __builtin_amdgcn_mfma_f32_16x16x32_bf16(af[mf], bf[nf], acc[mf][nf], 0, 0, 0);
    __builtin_amdgcn_s_setprio(0);
    __builtin_amdgcn_s_barrier();

    // ---- P2 (ks=1): stage B(u+2); counted vmcnt ----
#pragma unroll
    for (int mf = 0; mf < 4; mf++) af[mf] = lA[buf][((wm * 4 + mf) * 2 + 1) * 64 + l];
#pragma unroll
    for (int nf = 0; nf < 4; nf++) bf[nf] = lB[vb][((wn * 4 + nf) * 2 + 1) * 64 + l];
    stageB((u + 2) % 3, kB);
    __builtin_amdgcn_s_barrier();
    __builtin_amdgcn_s_setprio(1);
#pragma unroll
    for (int mf = 0; mf < 4; mf++)
#pragma unroll
      for (int nf = 0; nf < 4; nf++)
        acc[mf][nf] = __builtin_amdgcn_mfma_f32_16x16x32_bf16(af[mf], bf[nf], acc[mf][nf], 0, 0, 0);
    __builtin_amdgcn_s_setprio(0);
    asm volatile("s_waitcnt vmcnt(4)" ::: "memory");
    __builtin_amdgcn_s_barrier();
  }
  asm volatile("s_waitcnt vmcnt(0)" ::: "memory");   // drain tail dummies

  const float qsc = 0.18033688011112042f;  // d^-0.5 * log2(e)
#pragma unroll
  for (int nf = 0; nf < 4; nf++) {
    int gn = n0 + wn * 64 + nf * 16 + lr;
    int sel = gn >> 10;
    int h = (gn >> 6) & 15;
    int d = gn & 63;
    float sc = (sel == 0) ? qsc : 1.0f;
    u16* dst = QKV + (size_t)sel * 8388608 + ((size_t)h * 2048) * 64 + d;
#pragma unroll
    for (int mf = 0; mf < 4; mf++) {
#pragma unroll
      for (int r = 0; r < 4; r++) {
        int gm = m0 + wm * 64 + mf * 16 + lq * 4 + r;
        int b = gm >> 11, s = gm & 2047;
        dst[((size_t)b * 16 * 2048 + s) * 64] = f2b(acc[mf][nf][r] * sc);
      }
    }
  }
}

// ---------------- gemm_out: same template, N=1024, grid 256 = 1 round ----------------

__global__ __launch_bounds__(512, 2) void gemm_out_kernel(
    const u16* __restrict__ A, const u16* __restrict__ Bt,
    const float* __restrict__ bias, float* __restrict__ out) {
  const int K = 1024;
  const int NT = 16;
  __shared__ short8 lA[2][1024];
  __shared__ short8 lB[3][2048];
  int tid = threadIdx.x;
  int wid = tid >> 6, l = tid & 63, lr = l & 15, lq = l >> 4;
  int wm = wid >> 2, wn = wid & 3;
  int gid = blockIdx.x;
  int xcd = gid & 7, j = gid >> 3;    // 32 blocks per XCD
  int nt = j % 4, mt = xcd * 8 + j / 4;
  int m0 = mt * 128, n0 = nt * 256;

  float4_ acc[4][4] = {};

  const u16* srcA[2];
  const u16* srcB[4];
#pragma unroll
  for (int s = 0; s < 2; s++) {
    int fl = s * 8 + wid;
    srcA[s] = A + (size_t)(m0 + (fl >> 1) * 16 + lr) * K + (fl & 1) * 32 + lq * 8;
  }
#pragma unroll
  for (int s = 0; s < 4; s++) {
    int fl = s * 8 + wid;
    srcB[s] = Bt + (size_t)(n0 + (fl >> 1) * 16 + lr) * K + (fl & 1) * 32 + lq * 8;
  }

  auto stageA = [&](int buf, int k0) {
#pragma unroll
    for (int s = 0; s < 2; s++)
      async_cp16(srcA[s] + k0, &lA[buf][(s * 8 + wid) * 64 + l]);
  };
  auto stageB = [&](int bb, int k0) {
#pragma unroll
    for (int s = 0; s < 4; s++)
      async_cp16(srcB[s] + k0, &lB[bb][(s * 8 + wid) * 64 + l]);
  };

  stageA(0, 0);
  stageB(0, 0);
  stageB(1, 64);
  asm volatile("s_waitcnt vmcnt(4)" ::: "memory");
  __builtin_amdgcn_s_barrier();

  for (int u = 0; u < NT; ++u) {
    int buf = u & 1;
    int vb = u % 3;
    int kA = (u + 1 < NT ? u + 1 : NT - 1) * 64;
    int kB = (u + 2 < NT ? u + 2 : NT - 1) * 64;
    short8 af[4], bf[4];

#pragma unroll
    for (int mf = 0; mf < 4; mf++) af[mf] = lA[buf][((wm * 4 + mf) * 2 + 0) * 64 + l];
#pragma unroll
    for (int nf = 0; nf < 4; nf++) bf[nf] = lB[vb][((wn * 4 + nf) * 2 + 0) * 64 + l];
    stageA(buf ^ 1, kA);
    __builtin_amdgcn_s_barrier();
    __builtin_amdgcn_s_setprio(1);
#pragma unroll
    for (int mf = 0; mf < 4; mf++)
#pragma unroll
      for (int nf = 0; nf < 4; nf++)
        acc[mf][nf] = __builtin_amdgcn_mfma_f32_16x16x32_bf16(af[mf], bf[nf], acc[mf][nf], 0, 0, 0);
    __builtin_amdgcn_s_setprio(0);
    __builtin_amdgcn_s_barrier();

#pragma unroll
    for (int mf = 0; mf < 4; mf++) af[mf] = lA[buf][((wm * 4 + mf) * 2 + 1) * 64 + l];
#pragma unroll
    for (int nf = 0; nf < 4; nf++) bf[nf] = lB[vb][((wn * 4 + nf) * 2 + 1) * 64 + l];
    stageB((u + 2) % 3, kB);
    __builtin_amdgcn_s_barrier();
    __builtin_amdgcn_s_setprio(1);
#pragma unroll
    for (int mf = 0; mf < 4; mf++)
#pragma unroll
      for (int nf = 0; nf < 4; nf++)
        acc[mf][nf] = __builtin_amdgcn_mfma_f32_16x16x32_bf16(af[mf], bf[nf], acc[mf][nf], 0, 0, 0);
    __builtin_amdgcn_s_setprio(0);
    asm volatile("s_waitcnt vmcnt(4)" ::: "memory");
    __builtin_amdgcn_s_barrier();
  }
  asm volatile("s_waitcnt vmcnt(0)" ::: "memory");

#pragma unroll
  for (int nf = 0; nf < 4; nf++) {
    int gn = n0 + wn * 64 + nf * 16 + lr;
    float bv = bias[gn];
#pragma unroll
    for (int mf = 0; mf < 4; mf++)
#pragma unroll
      for (int r = 0; r < 4; r++) {
        int gm = m0 + wm * 64 + mf * 16 + lq * 4 + r;
        out[(size_t)gm * 1024 + gn] = acc[mf][nf][r] + bv;
      }
  }
}

// ---------------- flash attention (block-cooperative, dbuf LDS K/V) ----------------
// Unchanged from R8. Block = 4 waves = 128 q rows. KV-step 64, double-buffered.
// Q pre-scaled by d^-0.5*log2e => P = exp2(S). Grid 1024, XCD-swizzled.

__global__ __launch_bounds__(256) void attn_kernel(
    const u16* __restrict__ Qb, const u16* __restrict__ Kb,
    const u16* __restrict__ Vt, u16* __restrict__ Ob) {
  const int S = 2048, D = 64;
  __shared__ short8 lK[2][512];            // 16 KB
  __shared__ short8 lV[2][512];            // 16 KB
  __shared__ __align__(16) u32 pb[4][16][20];   // 5 KB
  int tid = threadIdx.x;
  int w = tid >> 6, l = tid & 63, lr = l & 15, lq = l >> 4;
  int gid = blockIdx.x;
  int xcd = gid & 7, j = gid >> 3;        // j in [0,128)
  int bh = xcd * 8 + (j >> 4);            // qblk-major: consecutive j share bh
  int qblk = j & 15;                      // 0..15
  int q0 = qblk * 128 + w * 32;
  const u16* Qh = Qb + (size_t)bh * S * D;
  const u16* Kh = Kb + (size_t)bh * S * D;
  const u16* Vh = Vt + (size_t)bh * D * S;

  short8 qf[2][2];
#pragma unroll
  for (int qg = 0; qg < 2; qg++) {
    qf[qg][0] = *(const short8*)(Qh + (q0 + qg * 16 + lr) * D + lq * 8);
    qf[qg][1] = *(const short8*)(Qh + (q0 + qg * 16 + lr) * D + 32 + lq * 8);
  }

  float ls[2][4] = {};
  float4_ o[2][4] = {};

  const u16* kg = Kh + (size_t)(((w >> 1) << 5) + 2 * lr + (w & 1)) * D + lq * 8;
  const u16* vg = Vh + (size_t)(w * 16 + lr) * S + lq * 8;

  auto stage = [&](int buf, int kv0) {
    async_cp16(kg + (size_t)kv0 * D, &lK[buf][(w * 2 + 0) * 64 + l]);
    async_cp16(kg + (size_t)kv0 * D + 32, &lK[buf][(w * 2 + 1) * 64 + l]);
    async_cp16(vg + kv0, &lV[buf][(w * 2 + 0) * 64 + l]);
    async_cp16(vg + kv0 + 32, &lV[buf][(w * 2 + 1) * 64 + l]);
  };

  auto compute = [&](int buf) {
#pragma unroll
    for (int sub = 0; sub < 2; sub++) {
      short8 ke0 = lK[buf][((sub * 2 + 0) * 2 + 0) * 64 + l];  // even rows, d 0..31
      short8 ke1 = lK[buf][((sub * 2 + 0) * 2 + 1) * 64 + l];  // even rows, d 32..63
      short8 ko0 = lK[buf][((sub * 2 + 1) * 2 + 0) * 64 + l];  // odd rows,  d 0..31
      short8 ko1 = lK[buf][((sub * 2 + 1) * 2 + 1) * 64 + l];  // odd rows,  d 32..63
#pragma unroll
      for (int qg = 0; qg < 2; qg++) {
        float4_ z = {0.f, 0.f, 0.f, 0.f};
        float4_ s0 = __builtin_amdgcn_mfma_f32_16x16x32_bf16(qf[qg][0], ke0, z, 0, 0, 0);
        s0 = __builtin_amdgcn_mfma_f32_16x16x32_bf16(qf[qg][1], ke1, s0, 0, 0, 0);
        float4_ s1 = __builtin_amdgcn_mfma_f32_16x16x32_bf16(qf[qg][0], ko0, z, 0, 0, 0);
        s1 = __builtin_amdgcn_mfma_f32_16x16x32_bf16(qf[qg][1], ko1, s1, 0, 0, 0);
#pragma unroll
        for (int r = 0; r < 4; r++) {
          float p0 = fexp2(s0[r]);
          float p1 = fexp2(s1[r]);
          u32 pk = pk_trunc(p0, p1);
          ls[qg][r] = accum_pk(pk, ls[qg][r]);  // rounded values: bias cancels
          pb[w][lq * 4 + r][lr] = pk;
        }
        short8 pa = *(const short8*)&pb[w][lr][lq * 4];  // A-frag: row lr, kv lq*8..+7
#pragma unroll
        for (int dt = 0; dt < 4; dt++)
          o[qg][dt] = __builtin_amdgcn_mfma_f32_16x16x32_bf16(
              pa, lV[buf][(dt * 2 + sub) * 64 + l], o[qg][dt], 0, 0, 0);
      }
    }
  };

  stage(0, 0);
  for (int kv0 = 0; kv0 < S; kv0 += 128) {
    __syncthreads();
    stage(1, kv0 + 64);
    compute(0);
    __syncthreads();
    if (kv0 + 128 < S) stage(0, kv0 + 128);
    compute(1);
  }

  int b = bh >> 4, h = bh & 15;
#pragma unroll
  for (int qg = 0; qg < 2; qg++) {
    float inv[4];
#pragma unroll
    for (int r = 0; r < 4; r++) {
      float s = ls[qg][r];
#pragma unroll
      for (int off = 1; off < 16; off <<= 1) s += __shfl_xor(s, off, 64);
      inv[r] = 1.0f / s;
    }
#pragma unroll
    for (int dt = 0; dt < 4; dt++)
#pragma unroll
      for (int r = 0; r < 4; r++) {
        int s_ = q0 + qg * 16 + lq * 4 + r;
        Ob[((size_t)(b * 2048 + s_)) * 1024 + h * 64 + dt * 16 + lr] =
            f2b(o[qg][dt][r] * inv[r]);
      }
  }
}

// ---------------- launch ----------------

extern "C" void kernel_launch(void* const* d_in, const int* in_sizes, int n_in,
                              void* d_out, int out_size, void* d_ws, size_t ws_size,
                              hipStream_t stream) {
  const float* x     = (const float*)d_in[0];   // [4,2048,1024]
  const float* w_qkv = (const float*)d_in[1];   // [1024,3072]
  const float* w_out = (const float*)d_in[2];   // [1024,1024]
  const float* b_out = (const float*)d_in[3];   // [1024]
  float* out = (float*)d_out;

  char* ws = (char*)d_ws;
  u16* Xb  = (u16*)(ws);                    // 16 MB (x bf16; reused as O)
  u16* Wqt = (u16*)(ws + (16u << 20));      // 6 MB  (w_qkv^T bf16)
  u16* Wot = (u16*)(ws + (22u << 20));      // 2 MB  (w_out^T bf16)
  u16* QKV = (u16*)(ws + (24u << 20));      // 48 MB: Q | K | V  (each [b,h,s,d])
  u16* Qb  = QKV;
  u16* Kb  = QKV + 8388608;
  u16* Vb  = QKV + 16777216;
  u16* Vt  = (u16*)(ws + (72u << 20));      // 16 MB [b,h,d,s] -> 88 MB total
  u16* Ob  = Xb;                            // O overwrites Xb

  prepass_kernel<<<12288, 256, 0, stream>>>(x, Xb, w_qkv, Wqt, w_out, Wot);
  gemm_qkv_kernel<<<768, 512, 0, stream>>>(Xb, Wqt, QKV);
  transpose_v<<<dim3(32, 64), 256, 0, stream>>>(Vb, Vt);
  attn_kernel<<<1024, 256, 0, stream>>>(Qb, Kb, Vt, Ob);
  gemm_out_kernel<<<256, 512, 0, stream>>>(Ob, Wot, b_out, out);
}

// Round 4
// 339.905 us; speedup vs baseline: 1.0076x; 1.0076x over previous
//
#include <hip/hip_runtime.h>
#include <cstdint>
#include <cstddef>

// MI355X self-attention: B=4 S=2048 E=1024 H=16 D=64
// R11 = R10 resubmit (R10 bench died to container/infra failure, no data).
//  GEMM stall diagnosis: per-block staging is latency-bound (~9 B/cyc/blk
//  exposed load latency); R8/R9 ran 1 block/CU so nothing covered it.
//  Template: BM=BN=128 BK=64, 256 thr / 4 waves, 64KB LDS dbuf ->
//  2 blocks/CU; one vmcnt(8)+barrier per K-tile (own-tile landed, next tile
//  in flight), stage tile u+2 after consumption barrier; compiler-scheduled
//  ds_read/MFMA interleave (no lgkm fences). 2D-patch XCD mapping: each XCD
//  owns an 8-mt slice (2MB A L2-resident), concurrent window = 8x8 patch.
//  attn/prepass/transpose_v unchanged from R9 (passing).

typedef __attribute__((ext_vector_type(8))) short short8;   // 8 x bf16
typedef __attribute__((ext_vector_type(4))) float float4_;
typedef unsigned int u32;
typedef unsigned short u16;

__device__ __forceinline__ u16 f2b(float f) {
  u32 u = __float_as_uint(f);
  u += 0x7FFFu + ((u >> 16) & 1u);   // RNE
  return (u16)(u >> 16);
}

__device__ __forceinline__ float fexp2(float x) {
#if __has_builtin(__builtin_amdgcn_exp2f)
  return __builtin_amdgcn_exp2f(x);   // bare v_exp_f32
#else
  return exp2f(x);
#endif
}

// pack (lo,hi) floats -> bf16x2 by truncation (1 v_perm)
__device__ __forceinline__ u32 pk_trunc(float lo, float hi) {
#if __has_builtin(__builtin_amdgcn_perm)
  return __builtin_amdgcn_perm(__float_as_uint(hi), __float_as_uint(lo), 0x07060302);
#else
  return (__float_as_uint(hi) & 0xFFFF0000u) | (__float_as_uint(lo) >> 16);
#endif
}

#if __has_builtin(__builtin_amdgcn_fdot2_f32_bf16)
typedef __bf16 bf16x2 __attribute__((ext_vector_type(2)));
__device__ __forceinline__ float accum_pk(u32 pk, float acc) {
  bf16x2 p = __builtin_bit_cast(bf16x2, pk);
  bf16x2 one = __builtin_bit_cast(bf16x2, (u32)0x3F803F80u);
  return __builtin_amdgcn_fdot2_f32_bf16(p, one, acc, false);
}
#else
__device__ __forceinline__ float accum_pk(u32 pk, float acc) {
  return acc + __uint_as_float(pk << 16) + __uint_as_float(pk & 0xFFFF0000u);
}
#endif

// async global->LDS, 16B per lane; LDS dst must be wave-uniform base + lane*16
__device__ __forceinline__ void async_cp16(const void* g, void* l) {
  __builtin_amdgcn_global_load_lds(
      (const __attribute__((address_space(1))) u32*)g,
      (__attribute__((address_space(3))) u32*)l, 16, 0, 0);
}

// ---------------- fused pre-pass ----------------
// blocks [0,8192): cvt x->bf16; [8192,11264): transpose w_qkv; rest: w_out.

__device__ __forceinline__ void transpose_block(const float* __restrict__ in,
                                                u16* __restrict__ out,
                                                int R, int C, int bx, int by,
                                                float t[32][33]) {
  int tx = threadIdx.x & 31, ty = threadIdx.x >> 5;
  int r0 = by * 32, c0 = bx * 32;
#pragma unroll
  for (int k = 0; k < 4; k++)
    t[ty + 8 * k][tx] = in[(size_t)(r0 + ty + 8 * k) * C + c0 + tx];
  __syncthreads();
#pragma unroll
  for (int k = 0; k < 4; k++)
    out[(size_t)(c0 + ty + 8 * k) * R + r0 + tx] = f2b(t[tx][ty + 8 * k]);
}

__global__ void prepass_kernel(const float* __restrict__ x, u16* __restrict__ Xb,
                               const float* __restrict__ wqkv, u16* __restrict__ Wqt,
                               const float* __restrict__ wout, u16* __restrict__ Wot) {
  __shared__ float t[32][33];
  int gid = blockIdx.x;
  if (gid < 8192) {
    int i = gid * 256 + threadIdx.x;
    float4 v = ((const float4*)x)[i];
    uint2 p;
    p.x = (u32)f2b(v.x) | ((u32)f2b(v.y) << 16);
    p.y = (u32)f2b(v.z) | ((u32)f2b(v.w) << 16);
    ((uint2*)Xb)[i] = p;
  } else if (gid < 11264) {
    int j = gid - 8192;
    transpose_block(wqkv, Wqt, 1024, 3072, j % 96, j / 96, t);
  } else {
    int j = gid - 11264;
    transpose_block(wout, Wot, 1024, 1024, j % 32, j / 32, t);
  }
}

// V[bh][s][d] bf16 -> Vt[bh][d][s] bf16. 64x64 tiles. grid (32, 64), block 256.
__global__ void transpose_v(const u16* __restrict__ V, u16* __restrict__ Vt) {
  __shared__ u16 t[64][80];
  int bh = blockIdx.y, s0 = blockIdx.x * 64;
  const u16* Vh = V + (size_t)bh * 2048 * 64;
  u16* Vth = Vt + (size_t)bh * 64 * 2048;
  int tr = threadIdx.x >> 3;            // 0..31
  int tc = (threadIdx.x & 7) * 8;       // 0..56 step 8
#pragma unroll
  for (int p = 0; p < 2; p++) {
    int r = p * 32 + tr;
    *(uint4*)&t[r][tc] = *(const uint4*)(Vh + (size_t)(s0 + r) * 64 + tc);
  }
  __syncthreads();
#pragma unroll
  for (int p = 0; p < 2; p++) {
    int d = p * 32 + tr;
    u16 tmp[8];
#pragma unroll
    for (int k = 0; k < 8; k++) tmp[k] = t[tc + k][d];
    *(uint4*)(Vth + (size_t)d * 2048 + s0 + tc) = *(uint4*)tmp;
  }
}

// ---------------- GEMM template: 128x128, BK=64, 2 blocks/CU, depth-2 prefetch ----
// LDS fragment-major chunks: chunk fl = fr*2+ks holds M[base+fr*16+lr][ks*32+lq*8..+8]
// at lX[buf][fl*64 + lane]; staged linearly by global_load_lds (per-lane
// pre-swizzled global source). Per wave per stage: 4 A-loads + 4 B-loads.
// Iter u: vmcnt(8) [tile u landed, tile u+1 (8/wave) in flight]; s_barrier;
//         16 ds_read_b128 + 32 MFMA (compiler-interleaved); s_barrier;
//         stage tile u+2 into buf just consumed. Tail stages clamp to NT-1
//         (harmless dup writes) so vmcnt counts stay uniform.

__global__ __launch_bounds__(256, 2) void gemm_qkv_kernel(
    const u16* __restrict__ A, const u16* __restrict__ Bt,
    u16* __restrict__ QKV) {   // QKV = 3 x 16MB consecutive [b,h,s,d] buffers
  const int K = 1024;
  const int NT = 16;                  // K / 64
  __shared__ short8 lA[2][1024];      // 32 KB
  __shared__ short8 lB[2][1024];      // 32 KB
  int tid = threadIdx.x;
  int wid = tid >> 6, l = tid & 63, lr = l & 15, lq = l >> 4;
  int wm = wid & 1, wn = wid >> 1;    // 2 x 2 wave grid
  int gid = blockIdx.x;
  int xcd = gid & 7, j = gid >> 3;    // 192 blocks per XCD
  int mt = xcd * 8 + (j & 7);         // XCD owns 8-mt slice (2MB A, L2-resident)
  int nt = j >> 3;                    // 0..23, concurrent window = 8x8 patch
  int m0 = mt * 128, n0 = nt * 128;

  float4_ acc[4][4] = {};

  const u16* srcA[4];
  const u16* srcB[4];
#pragma unroll
  for (int s = 0; s < 4; s++) {
    int fl = s * 4 + wid;             // chunk this (wave,s) stages
    srcA[s] = A + (size_t)(m0 + (fl >> 1) * 16 + lr) * K + (fl & 1) * 32 + lq * 8;
    srcB[s] = Bt + (size_t)(n0 + (fl >> 1) * 16 + lr) * K + (fl & 1) * 32 + lq * 8;
  }

  auto stage = [&](int buf, int k0) {
#pragma unroll
    for (int s = 0; s < 4; s++)
      async_cp16(srcA[s] + k0, &lA[buf][(s * 4 + wid) * 64 + l]);
#pragma unroll
    for (int s = 0; s < 4; s++)
      async_cp16(srcB[s] + k0, &lB[buf][(s * 4 + wid) * 64 + l]);
  };

  stage(0, 0);
  stage(1, 64);                       // 16 loads/wave outstanding

  for (int u = 0; u < NT; ++u) {
    int buf = u & 1;
    asm volatile("s_waitcnt vmcnt(8)" ::: "memory");   // tile u landed
    __builtin_amdgcn_s_barrier();                      // all waves' loads landed
    short8 af[4], bf[4];
#pragma unroll
    for (int ks = 0; ks < 2; ks++) {
#pragma unroll
      for (int mf = 0; mf < 4; mf++) af[mf] = lA[buf][((wm * 4 + mf) * 2 + ks) * 64 + l];
#pragma unroll
      for (int nf = 0; nf < 4; nf++) bf[nf] = lB[buf][((wn * 4 + nf) * 2 + ks) * 64 + l];
#pragma unroll
      for (int mf = 0; mf < 4; mf++)
#pragma unroll
        for (int nf = 0; nf < 4; nf++)
          acc[mf][nf] = __builtin_amdgcn_mfma_f32_16x16x32_bf16(af[mf], bf[nf], acc[mf][nf], 0, 0, 0);
    }
    __builtin_amdgcn_s_barrier();                      // buf fully consumed
    int kn = (u + 2 < NT ? u + 2 : NT - 1) * 64;       // clamp: dup-write tail
    stage(buf, kn);                                    // overwrite consumed buf
  }
  asm volatile("s_waitcnt vmcnt(0)" ::: "memory");     // drain tail dummies

  const float qsc = 0.18033688011112042f;  // d^-0.5 * log2(e)
#pragma unroll
  for (int nf = 0; nf < 4; nf++) {
    int gn = n0 + wn * 64 + nf * 16 + lr;
    int sel = gn >> 10;
    int h = (gn >> 6) & 15;
    int d = gn & 63;
    float sc = (sel == 0) ? qsc : 1.0f;
    u16* dst = QKV + (size_t)sel * 8388608 + ((size_t)h * 2048) * 64 + d;
#pragma unroll
    for (int mf = 0; mf < 4; mf++) {
#pragma unroll
      for (int r = 0; r < 4; r++) {
        int gm = m0 + wm * 64 + mf * 16 + lq * 4 + r;
        int b = gm >> 11, s = gm & 2047;
        dst[((size_t)b * 16 * 2048 + s) * 64] = f2b(acc[mf][nf][r] * sc);
      }
    }
  }
}

__global__ __launch_bounds__(256, 2) void gemm_out_kernel(
    const u16* __restrict__ A, const u16* __restrict__ Bt,
    const float* __restrict__ bias, float* __restrict__ out) {
  const int K = 1024;
  const int NT = 16;
  __shared__ short8 lA[2][1024];
  __shared__ short8 lB[2][1024];
  int tid = threadIdx.x;
  int wid = tid >> 6, l = tid & 63, lr = l & 15, lq = l >> 4;
  int wm = wid & 1, wn = wid >> 1;
  int gid = blockIdx.x;
  int xcd = gid & 7, j = gid >> 3;    // 64 blocks per XCD
  int mt = xcd * 8 + (j & 7);
  int nt = j >> 3;                    // 0..7
  int m0 = mt * 128, n0 = nt * 128;

  float4_ acc[4][4] = {};

  const u16* srcA[4];
  const u16* srcB[4];
#pragma unroll
  for (int s = 0; s < 4; s++) {
    int fl = s * 4 + wid;
    srcA[s] = A + (size_t)(m0 + (fl >> 1) * 16 + lr) * K + (fl & 1) * 32 + lq * 8;
    srcB[s] = Bt + (size_t)(n0 + (fl >> 1) * 16 + lr) * K + (fl & 1) * 32 + lq * 8;
  }

  auto stage = [&](int buf, int k0) {
#pragma unroll
    for (int s = 0; s < 4; s++)
      async_cp16(srcA[s] + k0, &lA[buf][(s * 4 + wid) * 64 + l]);
#pragma unroll
    for (int s = 0; s < 4; s++)
      async_cp16(srcB[s] + k0, &lB[buf][(s * 4 + wid) * 64 + l]);
  };

  stage(0, 0);
  stage(1, 64);

  for (int u = 0; u < NT; ++u) {
    int buf = u & 1;
    asm volatile("s_waitcnt vmcnt(8)" ::: "memory");
    __builtin_amdgcn_s_barrier();
    short8 af[4], bf[4];
#pragma unroll
    for (int ks = 0; ks < 2; ks++) {
#pragma unroll
      for (int mf = 0; mf < 4; mf++) af[mf] = lA[buf][((wm * 4 + mf) * 2 + ks) * 64 + l];
#pragma unroll
      for (int nf = 0; nf < 4; nf++) bf[nf] = lB[buf][((wn * 4 + nf) * 2 + ks) * 64 + l];
#pragma unroll
      for (int mf = 0; mf < 4; mf++)
#pragma unroll
        for (int nf = 0; nf < 4; nf++)
          acc[mf][nf] = __builtin_amdgcn_mfma_f32_16x16x32_bf16(af[mf], bf[nf], acc[mf][nf], 0, 0, 0);
    }
    __builtin_amdgcn_s_barrier();
    int kn = (u + 2 < NT ? u + 2 : NT - 1) * 64;
    stage(buf, kn);
  }
  asm volatile("s_waitcnt vmcnt(0)" ::: "memory");

#pragma unroll
  for (int nf = 0; nf < 4; nf++) {
    int gn = n0 + wn * 64 + nf * 16 + lr;
    float bv = bias[gn];
#pragma unroll
    for (int mf = 0; mf < 4; mf++)
#pragma unroll
      for (int r = 0; r < 4; r++) {
        int gm = m0 + wm * 64 + mf * 16 + lq * 4 + r;
        out[(size_t)gm * 1024 + gn] = acc[mf][nf][r] + bv;
      }
  }
}

// ---------------- flash attention (block-cooperative, dbuf LDS K/V) ----------------
// Unchanged from R9. Block = 4 waves = 128 q rows. KV-step 64, double-buffered.
// Q pre-scaled by d^-0.5*log2e => P = exp2(S). Grid 1024, XCD-swizzled.

__global__ __launch_bounds__(256) void attn_kernel(
    const u16* __restrict__ Qb, const u16* __restrict__ Kb,
    const u16* __restrict__ Vt, u16* __restrict__ Ob) {
  const int S = 2048, D = 64;
  __shared__ short8 lK[2][512];            // 16 KB
  __shared__ short8 lV[2][512];            // 16 KB
  __shared__ __align__(16) u32 pb[4][16][20];   // 5 KB
  int tid = threadIdx.x;
  int w = tid >> 6, l = tid & 63, lr = l & 15, lq = l >> 4;
  int gid = blockIdx.x;
  int xcd = gid & 7, j = gid >> 3;        // j in [0,128)
  int bh = xcd * 8 + (j >> 4);            // qblk-major: consecutive j share bh
  int qblk = j & 15;                      // 0..15
  int q0 = qblk * 128 + w * 32;
  const u16* Qh = Qb + (size_t)bh * S * D;
  const u16* Kh = Kb + (size_t)bh * S * D;
  const u16* Vh = Vt + (size_t)bh * D * S;

  short8 qf[2][2];
#pragma unroll
  for (int qg = 0; qg < 2; qg++) {
    qf[qg][0] = *(const short8*)(Qh + (q0 + qg * 16 + lr) * D + lq * 8);
    qf[qg][1] = *(const short8*)(Qh + (q0 + qg * 16 + lr) * D + 32 + lq * 8);
  }

  float ls[2][4] = {};
  float4_ o[2][4] = {};

  const u16* kg = Kh + (size_t)(((w >> 1) << 5) + 2 * lr + (w & 1)) * D + lq * 8;
  const u16* vg = Vh + (size_t)(w * 16 + lr) * S + lq * 8;

  auto stage = [&](int buf, int kv0) {
    async_cp16(kg + (size_t)kv0 * D, &lK[buf][(w * 2 + 0) * 64 + l]);
    async_cp16(kg + (size_t)kv0 * D + 32, &lK[buf][(w * 2 + 1) * 64 + l]);
    async_cp16(vg + kv0, &lV[buf][(w * 2 + 0) * 64 + l]);
    async_cp16(vg + kv0 + 32, &lV[buf][(w * 2 + 1) * 64 + l]);
  };

  auto compute = [&](int buf) {
#pragma unroll
    for (int sub = 0; sub < 2; sub++) {
      short8 ke0 = lK[buf][((sub * 2 + 0) * 2 + 0) * 64 + l];  // even rows, d 0..31
      short8 ke1 = lK[buf][((sub * 2 + 0) * 2 + 1) * 64 + l];  // even rows, d 32..63
      short8 ko0 = lK[buf][((sub * 2 + 1) * 2 + 0) * 64 + l];  // odd rows,  d 0..31
      short8 ko1 = lK[buf][((sub * 2 + 1) * 2 + 1) * 64 + l];  // odd rows,  d 32..63
#pragma unroll
      for (int qg = 0; qg < 2; qg++) {
        float4_ z = {0.f, 0.f, 0.f, 0.f};
        float4_ s0 = __builtin_amdgcn_mfma_f32_16x16x32_bf16(qf[qg][0], ke0, z, 0, 0, 0);
        s0 = __builtin_amdgcn_mfma_f32_16x16x32_bf16(qf[qg][1], ke1, s0, 0, 0, 0);
        float4_ s1 = __builtin_amdgcn_mfma_f32_16x16x32_bf16(qf[qg][0], ko0, z, 0, 0, 0);
        s1 = __builtin_amdgcn_mfma_f32_16x16x32_bf16(qf[qg][1], ko1, s1, 0, 0, 0);
#pragma unroll
        for (int r = 0; r < 4; r++) {
          float p0 = fexp2(s0[r]);
          float p1 = fexp2(s1[r]);
          u32 pk = pk_trunc(p0, p1);
          ls[qg][r] = accum_pk(pk, ls[qg][r]);  // rounded values: bias cancels
          pb[w][lq * 4 + r][lr] = pk;
        }
        short8 pa = *(const short8*)&pb[w][lr][lq * 4];  // A-frag: row lr, kv lq*8..+7
#pragma unroll
        for (int dt = 0; dt < 4; dt++)
          o[qg][dt] = __builtin_amdgcn_mfma_f32_16x16x32_bf16(
              pa, lV[buf][(dt * 2 + sub) * 64 + l], o[qg][dt], 0, 0, 0);
      }
    }
  };

  stage(0, 0);
  for (int kv0 = 0; kv0 < S; kv0 += 128) {
    __syncthreads();
    stage(1, kv0 + 64);
    compute(0);
    __syncthreads();
    if (kv0 + 128 < S) stage(0, kv0 + 128);
    compute(1);
  }

  int b = bh >> 4, h = bh & 15;
#pragma unroll
  for (int qg = 0; qg < 2; qg++) {
    float inv[4];
#pragma unroll
    for (int r = 0; r < 4; r++) {
      float s = ls[qg][r];
#pragma unroll
      for (int off = 1; off < 16; off <<= 1) s += __shfl_xor(s, off, 64);
      inv[r] = 1.0f / s;
    }
#pragma unroll
    for (int dt = 0; dt < 4; dt++)
#pragma unroll
      for (int r = 0; r < 4; r++) {
        int s_ = q0 + qg * 16 + lq * 4 + r;
        Ob[((size_t)(b * 2048 + s_)) * 1024 + h * 64 + dt * 16 + lr] =
            f2b(o[qg][dt][r] * inv[r]);
      }
  }
}

// ---------------- launch ----------------

extern "C" void kernel_launch(void* const* d_in, const int* in_sizes, int n_in,
                              void* d_out, int out_size, void* d_ws, size_t ws_size,
                              hipStream_t stream) {
  const float* x     = (const float*)d_in[0];   // [4,2048,1024]
  const float* w_qkv = (const float*)d_in[1];   // [1024,3072]
  const float* w_out = (const float*)d_in[2];   // [1024,1024]
  const float* b_out = (const float*)d_in[3];   // [1024]
  float* out = (float*)d_out;

  char* ws = (char*)d_ws;
  u16* Xb  = (u16*)(ws);                    // 16 MB (x bf16; reused as O)
  u16* Wqt = (u16*)(ws + (16u << 20));      // 6 MB  (w_qkv^T bf16)
  u16* Wot = (u16*)(ws + (22u << 20));      // 2 MB  (w_out^T bf16)
  u16* QKV = (u16*)(ws + (24u << 20));      // 48 MB: Q | K | V  (each [b,h,s,d])
  u16* Qb  = QKV;
  u16* Kb  = QKV + 8388608;
  u16* Vb  = QKV + 16777216;
  u16* Vt  = (u16*)(ws + (72u << 20));      // 16 MB [b,h,d,s] -> 88 MB total
  u16* Ob  = Xb;                            // O overwrites Xb

  prepass_kernel<<<12288, 256, 0, stream>>>(x, Xb, w_qkv, Wqt, w_out, Wot);
  gemm_qkv_kernel<<<1536, 256, 0, stream>>>(Xb, Wqt, QKV);
  transpose_v<<<dim3(32, 64), 256, 0, stream>>>(Vb, Vt);
  attn_kernel<<<1024, 256, 0, stream>>>(Qb, Kb, Vt, Ob);
  gemm_out_kernel<<<512, 256, 0, stream>>>(Ob, Wot, b_out, out);
}